// Round 1
// baseline (202.239 us; speedup 1.0000x reference)
//
#include <hip/hip_runtime.h>

typedef unsigned short u16;
typedef unsigned int u32;
typedef __attribute__((ext_vector_type(8))) short short8;
typedef __attribute__((ext_vector_type(4))) float f32x4;

#define LRELU_SLOPE 0.2f
#define EPS 1e-8f

// ---------- helpers ----------
static __device__ inline u32 cvt_pk_bf16(float lo, float hi) {
    u32 r;
    asm volatile("v_cvt_pk_bf16_f32 %0, %1, %2" : "=v"(r) : "v"(lo), "v"(hi));
    return r;
}
static __device__ inline u16 f2bf(float x) {
    u32 u = __float_as_uint(x);
    u += 0x7FFF + ((u >> 16) & 1);
    return (u16)(u >> 16);
}

// ---------- kernel 0: conv_w (512x512 f32, [k][n]) -> Wt (bf16, [n][k]) ----------
__global__ __launch_bounds__(256) void k_twt(const float* __restrict__ w, u16* __restrict__ wt) {
    int t = blockIdx.x * 256 + threadIdx.x;      // 0..262143
    int n = t >> 9, k = t & 511;
    wt[n * 512 + k] = f2bf(w[k * 512 + n]);
}

// ---------- kernel 1: GEMM + noise/bias/lrelu epilogue + stats ----------
// y[m][f] = lrelu( sum_k x[m][k]*W[k][f] + nw[f]*noise[m] + bias[f] )
// tile 128x128, BK=64, 4 waves (2x2), 4x4 16x16x32 frags per wave
__global__ __launch_bounds__(256) void k_gemm(
    const float* __restrict__ x, const u16* __restrict__ wt,
    const float* __restrict__ noise, const float* __restrict__ nw,
    const float* __restrict__ bias, float* __restrict__ y,
    float* __restrict__ sum, float* __restrict__ sumsq)
{
    __shared__ __align__(16) u16 Al[128 * 64];
    __shared__ __align__(16) u16 Bl[128 * 64];
    const int tid  = threadIdx.x;
    const int lane = tid & 63;
    const int wid  = tid >> 6;
    const int wm   = wid >> 1, wn = wid & 1;
    const int m0   = blockIdx.x * 128;
    const int n0   = blockIdx.y * 128;

    f32x4 acc[4][4] = {};

    for (int kb = 0; kb < 512; kb += 64) {
        // ---- stage A (x fp32 -> bf16, swizzled) ----
        #pragma unroll
        for (int j = 0; j < 4; ++j) {
            int uid = j * 256 + tid;
            int row = uid >> 3;
            int cp  = uid & 7;                 // LDS 16B slot
            int c   = cp ^ (row & 7);          // global 8-elem chunk
            const float* src = x + (size_t)(m0 + row) * 512 + kb + c * 8;
            float4 v0 = *(const float4*)src;
            float4 v1 = *(const float4*)(src + 4);
            uint4 o;
            o.x = cvt_pk_bf16(v0.x, v0.y);
            o.y = cvt_pk_bf16(v0.z, v0.w);
            o.z = cvt_pk_bf16(v1.x, v1.y);
            o.w = cvt_pk_bf16(v1.z, v1.w);
            *(uint4*)((char*)Al + row * 128 + cp * 16) = o;
        }
        // ---- stage B (Wt bf16, swizzled) ----
        #pragma unroll
        for (int j = 0; j < 4; ++j) {
            int uid = j * 256 + tid;
            int row = uid >> 3;
            int cp  = uid & 7;
            int c   = cp ^ (row & 7);
            uint4 v = *(const uint4*)(wt + (size_t)(n0 + row) * 512 + kb + c * 8);
            *(uint4*)((char*)Bl + row * 128 + cp * 16) = v;
        }
        __syncthreads();
        // ---- compute ----
        #pragma unroll
        for (int ks = 0; ks < 2; ++ks) {
            short8 af[4], bf[4];
            const int cidx = ks * 4 + (lane >> 4);
            #pragma unroll
            for (int mi = 0; mi < 4; ++mi) {
                int row = wm * 64 + mi * 16 + (lane & 15);
                af[mi] = *(const short8*)((char*)Al + row * 128 + ((cidx ^ (row & 7)) * 16));
            }
            #pragma unroll
            for (int ni = 0; ni < 4; ++ni) {
                int row = wn * 64 + ni * 16 + (lane & 15);
                bf[ni] = *(const short8*)((char*)Bl + row * 128 + ((cidx ^ (row & 7)) * 16));
            }
            #pragma unroll
            for (int mi = 0; mi < 4; ++mi)
                #pragma unroll
                for (int ni = 0; ni < 4; ++ni)
                    acc[mi][ni] = __builtin_amdgcn_mfma_f32_16x16x32_bf16(
                        af[mi], bf[ni], acc[mi][ni], 0, 0, 0);
        }
        __syncthreads();
    }

    // ---- epilogue: noise+bias+lrelu, write y fp32, accumulate stats ----
    const int b = m0 >> 12;                   // 4096 rows per batch image
    float nwv[4], bv[4];
    int colb[4];
    #pragma unroll
    for (int ni = 0; ni < 4; ++ni) {
        int col = n0 + wn * 64 + ni * 16 + (lane & 15);
        colb[ni] = col;
        nwv[ni] = nw[col];
        bv[ni]  = bias[col];
    }
    float ls[4] = {0, 0, 0, 0}, lq[4] = {0, 0, 0, 0};
    #pragma unroll
    for (int mi = 0; mi < 4; ++mi) {
        int rbase = m0 + wm * 64 + mi * 16 + (lane >> 4) * 4;
        #pragma unroll
        for (int r = 0; r < 4; ++r) {
            int row = rbase + r;
            float nz = noise[row];
            #pragma unroll
            for (int ni = 0; ni < 4; ++ni) {
                float v = acc[mi][ni][r] + nwv[ni] * nz + bv[ni];
                v = v > 0.0f ? v : LRELU_SLOPE * v;
                y[(size_t)row * 512 + colb[ni]] = v;
                ls[ni] += v;
                lq[ni] += v * v;
            }
        }
    }
    #pragma unroll
    for (int ni = 0; ni < 4; ++ni) {
        float s = ls[ni], q = lq[ni];
        s += __shfl_xor(s, 16); s += __shfl_xor(s, 32);
        q += __shfl_xor(q, 16); q += __shfl_xor(q, 32);
        if ((lane >> 4) == 0) {
            atomicAdd(&sum[b * 512 + colb[ni]], s);
            atomicAdd(&sumsq[b * 512 + colb[ni]], q);
        }
    }
}

// ---------- kernel 2: dense GEMM (gamma/beta) + stats finalize ----------
// per (b,f): A = (1+gamma)*rsqrt(var+eps), C = beta - mu*A
__global__ __launch_bounds__(256) void k_dense(
    const float* __restrict__ dl, const float* __restrict__ dw,
    const float* __restrict__ db, const float* __restrict__ sum,
    const float* __restrict__ sumsq, float* __restrict__ As, float* __restrict__ Cs)
{
    __shared__ float sg[256], sb[256];
    int tid = threadIdx.x;
    int p   = tid >> 3;                    // 0..31 pair within block
    int kc  = tid & 7;                     // 8-way k split
    int t   = blockIdx.x * 32 + p;         // (b,f) pair, 0..4095
    int b   = t >> 9, f = t & 511;
    const float* dlb = dl + b * 512;
    float g = 0.0f, be = 0.0f;
    #pragma unroll 8
    for (int i = 0; i < 64; ++i) {
        int k = kc * 64 + i;
        float dv = dlb[k];
        g  += dv * dw[k * 1024 + f];
        be += dv * dw[k * 1024 + 512 + f];
    }
    sg[tid] = g; sb[tid] = be;
    __syncthreads();
    if (kc == 0) {
        #pragma unroll
        for (int j = 1; j < 8; ++j) { g += sg[tid + j]; be += sb[tid + j]; }
        g  += db[f];
        be += db[512 + f];
        float mu  = sum[t]   * (1.0f / 4096.0f);
        float var = sumsq[t] * (1.0f / 4096.0f) - mu * mu;
        float inv = rsqrtf(var + EPS);
        float A = inv * (1.0f + g);
        As[t] = A;
        Cs[t] = be - mu * A;
    }
}

// ---------- kernel 3: in-place normalize + scale/shift ----------
__global__ __launch_bounds__(256) void k_norm(
    float* __restrict__ y, const float* __restrict__ As, const float* __restrict__ Cs)
{
    size_t i8 = (size_t)(blockIdx.x * 256 + threadIdx.x) * 8;
    int row = (int)(i8 >> 9);
    int f0  = (int)(i8 & 511);
    int b   = row >> 12;
    const float4 a0 = *(const float4*)(As + b * 512 + f0);
    const float4 a1 = *(const float4*)(As + b * 512 + f0 + 4);
    const float4 c0 = *(const float4*)(Cs + b * 512 + f0);
    const float4 c1 = *(const float4*)(Cs + b * 512 + f0 + 4);
    float4 v0 = *(float4*)(y + i8);
    float4 v1 = *(float4*)(y + i8 + 4);
    v0.x = v0.x * a0.x + c0.x;  v0.y = v0.y * a0.y + c0.y;
    v0.z = v0.z * a0.z + c0.z;  v0.w = v0.w * a0.w + c0.w;
    v1.x = v1.x * a1.x + c1.x;  v1.y = v1.y * a1.y + c1.y;
    v1.z = v1.z * a1.z + c1.z;  v1.w = v1.w * a1.w + c1.w;
    *(float4*)(y + i8)     = v0;
    *(float4*)(y + i8 + 4) = v1;
}

extern "C" void kernel_launch(void* const* d_in, const int* in_sizes, int n_in,
                              void* d_out, int out_size, void* d_ws, size_t ws_size,
                              hipStream_t stream) {
    const float* x     = (const float*)d_in[0];
    const float* dl    = (const float*)d_in[1];
    const float* noise = (const float*)d_in[2];
    const float* w     = (const float*)d_in[3];
    const float* nw    = (const float*)d_in[4];
    const float* bias  = (const float*)d_in[5];
    const float* dw    = (const float*)d_in[6];
    const float* db    = (const float*)d_in[7];
    float* out = (float*)d_out;

    char* ws = (char*)d_ws;
    u16*   wt    = (u16*)ws;                           // 512 KB
    float* sum   = (float*)(ws + 524288);              // 16 KB
    float* sumsq = (float*)(ws + 524288 + 16384);      // 16 KB
    float* As    = (float*)(ws + 524288 + 32768);      // 16 KB
    float* Cs    = (float*)(ws + 524288 + 49152);      // 16 KB

    hipMemsetAsync(sum, 0, 32768, stream);             // zero sum+sumsq
    k_twt  <<<1024, 256, 0, stream>>>(w, wt);
    k_gemm <<<dim3(256, 4), 256, 0, stream>>>(x, wt, noise, nw, bias, out, sum, sumsq);
    k_dense<<<128, 256, 0, stream>>>(dl, dw, db, sum, sumsq, As, Cs);
    k_norm <<<8192, 256, 0, stream>>>(out, As, Cs);
}